// Round 1
// baseline (4440.648 us; speedup 1.0000x reference)
//
#include <hip/hip_runtime.h>
#include <hip/hip_bf16.h>
#include <math.h>

#define NN 50000
#define NE 800000
#define NG 512
#define DIN 128
#define HD 256
#define DOUT 128
#define NL 5
#define H4 1024

__device__ __forceinline__ float gelu_exact(float x) {
    return 0.5f * x * (1.0f + erff(x * 0.70710678118654752f));
}

// ---------------- graph meta ----------------
__global__ void k_hist(const int* __restrict__ idx, int* __restrict__ cnt, int n) {
    int i = blockIdx.x * blockDim.x + threadIdx.x;
    if (i < n) atomicAdd(&cnt[idx[i]], 1);
}

// single-block exclusive scan, out has n+1 entries (out[n] = total)
__global__ void k_scan_excl(const int* __restrict__ in, int* __restrict__ out, int n) {
    __shared__ int buf[1024];
    __shared__ int carry_s;
    int tid = threadIdx.x;
    if (tid == 0) carry_s = 0;
    __syncthreads();
    for (int base = 0; base < n; base += 1024) {
        int i = base + tid;
        int v = (i < n) ? in[i] : 0;
        buf[tid] = v;
        __syncthreads();
        for (int off = 1; off < 1024; off <<= 1) {
            int t = (tid >= off) ? buf[tid - off] : 0;
            __syncthreads();
            buf[tid] += t;
            __syncthreads();
        }
        int inc = buf[tid];
        int tot = buf[1023];
        int c = carry_s;
        if (i < n) out[i] = c + inc - v;
        __syncthreads();
        if (tid == 0) carry_s = c + tot;
        __syncthreads();
    }
    if (tid == 0) out[n] = carry_s;
}

__global__ void k_fill_csr(const int* __restrict__ src, const int* __restrict__ dst,
                           const int* __restrict__ eoff, int* __restrict__ cursor,
                           int* __restrict__ csr, int n) {
    int e = blockIdx.x * blockDim.x + threadIdx.x;
    if (e < n) {
        int d = dst[e];
        int p = atomicAdd(&cursor[d], 1);
        csr[eoff[d] + p] = src[e];
    }
}

// ---------------- pooling / aggregation ----------------
__global__ void k_mean_pool(const float* __restrict__ h, const int* __restrict__ goff,
                            float* __restrict__ pool) {
    int g = blockIdx.x;
    int c = threadIdx.x;
    int s = goff[g], e = goff[g + 1];
    float acc = 0.f;
    for (int r = s; r < e; ++r) acc += h[(size_t)r * HD + c];
    int cnt = e - s;
    pool[g * HD + c] = acc / (float)(cnt > 0 ? cnt : 1);
}

__global__ void k_agg_add(const float* __restrict__ h, const int* __restrict__ eoff,
                          const int* __restrict__ csr, float* __restrict__ out) {
    int n = blockIdx.x;
    int c = threadIdx.x;
    int s = eoff[n], e = eoff[n + 1];
    float acc = h[(size_t)n * HD + c];
    for (int j = s; j < e; ++j) acc += h[(size_t)csr[j] * HD + c];
    out[(size_t)n * HD + c] = acc;
}

// ---------------- batch norm ----------------
__global__ void k_bn_stats(const float* __restrict__ h, float* __restrict__ s,
                           float* __restrict__ q, int rows, int rpb) {
    int c = threadIdx.x;
    int r0 = blockIdx.x * rpb;
    int r1 = min(r0 + rpb, rows);
    float a = 0.f, b = 0.f;
    for (int r = r0; r < r1; ++r) {
        float v = h[(size_t)r * HD + c];
        a += v; b += v * v;
    }
    atomicAdd(&s[c], a);
    atomicAdd(&q[c], b);
}

__global__ void k_bn_final(const float* __restrict__ s, const float* __restrict__ q,
                           const float* __restrict__ gamma, const float* __restrict__ beta,
                           float* __restrict__ scale, float* __restrict__ shift) {
    int c = threadIdx.x;
    float mu = s[c] * (1.0f / NN);
    float var = q[c] * (1.0f / NN) - mu * mu;
    float rs = rsqrtf(var + 1e-5f);
    float sc = rs * gamma[c];
    scale[c] = sc;
    shift[c] = beta[c] - mu * sc;
}

__global__ void k_bn_apply(const float* __restrict__ h, const float* __restrict__ scale,
                           const float* __restrict__ shift, const float* __restrict__ outvn,
                           const int* __restrict__ batch, float* __restrict__ A,
                           float* __restrict__ B) {
    int n = blockIdx.x;
    int c = threadIdx.x;
    float v = h[(size_t)n * HD + c] * scale[c] + shift[c];
    A[(size_t)n * HD + c] = v;
    B[(size_t)n * HD + c] = v + outvn[batch[n] * HD + c];
}

// ---------------- GEMM: C = epilogue(A @ W + bias [+bias2]) [+R] ----------------
template <bool GELU, bool RES, bool BIAS2>
__global__ __launch_bounds__(256) void k_gemm(const float* __restrict__ A,
                                              const float* __restrict__ W,
                                              const float* __restrict__ bias,
                                              const float* __restrict__ bias2,
                                              const float* __restrict__ R,
                                              float* __restrict__ C,
                                              int M, int K, int Nc) {
    __shared__ float As[16][64];
    __shared__ float Ws[16][64];
    int t = threadIdx.x;
    int m0 = blockIdx.y * 64, n0 = blockIdx.x * 64;
    int lr = t >> 2;          // A tile row 0..63
    int lk = (t & 3) << 2;    // A tile k  0,4,8,12
    int wr = t >> 4;          // W tile row 0..15
    int wc = (t & 15) << 2;   // W tile col 0..60
    int r0 = (t >> 4) << 2;   // micro-tile row
    int c0 = (t & 15) << 2;   // micro-tile col
    float acc[4][4] = {};
    for (int k0 = 0; k0 < K; k0 += 16) {
        float4 av;
        if (m0 + lr < M) av = *(const float4*)&A[(size_t)(m0 + lr) * K + k0 + lk];
        else av = make_float4(0.f, 0.f, 0.f, 0.f);
        float4 wv = *(const float4*)&W[(size_t)(k0 + wr) * Nc + n0 + wc];
        __syncthreads();
        As[lk + 0][lr] = av.x;
        As[lk + 1][lr] = av.y;
        As[lk + 2][lr] = av.z;
        As[lk + 3][lr] = av.w;
        *(float4*)&Ws[wr][wc] = wv;
        __syncthreads();
#pragma unroll
        for (int k = 0; k < 16; ++k) {
            float4 a = *(const float4*)&As[k][r0];
            float4 b = *(const float4*)&Ws[k][c0];
            acc[0][0] += a.x * b.x; acc[0][1] += a.x * b.y; acc[0][2] += a.x * b.z; acc[0][3] += a.x * b.w;
            acc[1][0] += a.y * b.x; acc[1][1] += a.y * b.y; acc[1][2] += a.y * b.z; acc[1][3] += a.y * b.w;
            acc[2][0] += a.z * b.x; acc[2][1] += a.z * b.y; acc[2][2] += a.z * b.z; acc[2][3] += a.z * b.w;
            acc[3][0] += a.w * b.x; acc[3][1] += a.w * b.y; acc[3][2] += a.w * b.z; acc[3][3] += a.w * b.w;
        }
    }
#pragma unroll
    for (int i = 0; i < 4; ++i) {
        int m = m0 + r0 + i;
        if (m < M) {
#pragma unroll
            for (int j = 0; j < 4; ++j) {
                int n = n0 + c0 + j;
                float v = acc[i][j] + bias[n];
                if (BIAS2) v += bias2[n];
                if (GELU) v = gelu_exact(v);
                if (RES) v += R[(size_t)m * Nc + n];
                C[(size_t)m * Nc + n] = v;
            }
        }
    }
}

static inline void launch_gemm(hipStream_t st, const float* A, const float* W,
                               const float* bias, const float* bias2, const float* R,
                               float* C, int M, int K, int Nc, bool gelu) {
    dim3 g((Nc + 63) / 64, (M + 63) / 64);
    dim3 b(256);
    if (gelu) {
        hipLaunchKernelGGL((k_gemm<true, false, false>), g, b, 0, st, A, W, bias, nullptr, nullptr, C, M, K, Nc);
    } else if (R != nullptr) {
        hipLaunchKernelGGL((k_gemm<false, true, false>), g, b, 0, st, A, W, bias, nullptr, R, C, M, K, Nc);
    } else if (bias2 != nullptr) {
        hipLaunchKernelGGL((k_gemm<false, false, true>), g, b, 0, st, A, W, bias, bias2, nullptr, C, M, K, Nc);
    } else {
        hipLaunchKernelGGL((k_gemm<false, false, false>), g, b, 0, st, A, W, bias, nullptr, nullptr, C, M, K, Nc);
    }
}

extern "C" void kernel_launch(void* const* d_in, const int* in_sizes, int n_in,
                              void* d_out, int out_size, void* d_ws, size_t ws_size,
                              hipStream_t stream) {
    const float* x       = (const float*)d_in[0];
    const int*   ei      = (const int*)d_in[1];
    const int*   batch   = (const int*)d_in[2];
    const float* pre_W1  = (const float*)d_in[3];
    const float* pre_b1  = (const float*)d_in[4];
    const float* pre_W2  = (const float*)d_in[5];
    const float* pre_b2  = (const float*)d_in[6];
    const float* gin_W1  = (const float*)d_in[7];
    const float* gin_b1  = (const float*)d_in[8];
    const float* gin_W2  = (const float*)d_in[9];
    const float* gin_b2  = (const float*)d_in[10];
    const float* ffn_W1  = (const float*)d_in[11];
    const float* ffn_b1  = (const float*)d_in[12];
    const float* ffn_W2  = (const float*)d_in[13];
    const float* ffn_b2  = (const float*)d_in[14];
    const float* upd_W1  = (const float*)d_in[15];
    const float* upd_b1  = (const float*)d_in[16];
    const float* upd_W2  = (const float*)d_in[17];
    const float* upd_b2  = (const float*)d_in[18];
    const float* prop_W1 = (const float*)d_in[19];
    const float* prop_b1 = (const float*)d_in[20];
    const float* prop_W2 = (const float*)d_in[21];
    const float* prop_b2 = (const float*)d_in[22];
    const float* bn_gamma= (const float*)d_in[23];
    const float* bn_beta = (const float*)d_in[24];
    const float* vn      = (const float*)d_in[25];
    const float* post_W1 = (const float*)d_in[26];
    const float* post_b1 = (const float*)d_in[27];
    const float* post_W2 = (const float*)d_in[28];
    const float* post_b2 = (const float*)d_in[29];
    float* out = (float*)d_out;

    const int* e_src = ei;
    const int* e_dst = ei + NE;

    // workspace layout
    size_t NH = (size_t)NN * HD;
    float* P0     = (float*)d_ws;
    float* P1     = P0 + NH;
    float* P2     = P1 + NH;
    float* poolb  = P2 + NH;            // NG*HD
    float* tsmall = poolb + (size_t)NG * HD;   // NG*HD
    float* vbuf   = tsmall + (size_t)NG * HD;  // NG*H4
    float* outvnb = vbuf + (size_t)NG * H4;    // NG*HD
    float* bnsum  = outvnb + (size_t)NG * HD;  // HD
    float* bnsq   = bnsum + HD;
    float* bnscale= bnsq + HD;
    float* bnshift= bnscale + HD;
    int* gcount = (int*)(bnshift + HD);        // NG
    int* goff   = gcount + NG;                 // NG+1
    int* deg    = goff + NG + 1;               // NN
    int* eoff   = deg + NN;                    // NN+1
    int* cursor = eoff + NN + 1;               // NN
    int* csr    = cursor + NN;                 // NE

    // zero the counters (gcount..cursor is contiguous)
    size_t zero_ints = (size_t)NG + (NG + 1) + NN + (NN + 1) + NN;
    hipMemsetAsync(gcount, 0, zero_ints * sizeof(int), stream);

    // graph meta
    hipLaunchKernelGGL(k_hist, dim3((NN + 255) / 256), dim3(256), 0, stream, batch, gcount, NN);
    hipLaunchKernelGGL(k_hist, dim3((NE + 255) / 256), dim3(256), 0, stream, e_dst, deg, NE);
    hipLaunchKernelGGL(k_scan_excl, dim3(1), dim3(1024), 0, stream, gcount, goff, NG);
    hipLaunchKernelGGL(k_scan_excl, dim3(1), dim3(1024), 0, stream, deg, eoff, NN);
    hipLaunchKernelGGL(k_fill_csr, dim3((NE + 255) / 256), dim3(256), 0, stream, e_src, e_dst, eoff, cursor, csr, NE);

    // pre-FFNN: h = P0
    launch_gemm(stream, x, pre_W1, pre_b1, nullptr, nullptr, P1, NN, DIN, HD, true);
    launch_gemm(stream, P1, pre_W2, pre_b2, nullptr, nullptr, P0, NN, HD, HD, false);

    float* h  = P0;
    float* f1 = P1;
    float* f2 = P2;

    for (int i = 0; i < NL; ++i) {
        const float* uW1 = upd_W1 + (size_t)i * HD * HD;
        const float* ub1 = upd_b1 + (size_t)i * HD;
        const float* uW2 = upd_W2 + (size_t)i * HD * H4;
        const float* ub2 = upd_b2 + (size_t)i * H4;
        const float* pW1 = prop_W1 + (size_t)i * H4 * HD;
        const float* pb1 = prop_b1 + (size_t)i * HD;
        const float* pW2 = prop_W2 + (size_t)i * HD * HD;
        const float* pb2 = prop_b2 + (size_t)i * HD;
        const float* gW1 = gin_W1 + (size_t)i * HD * HD;
        const float* gb1 = gin_b1 + (size_t)i * HD;
        const float* gW2 = gin_W2 + (size_t)i * HD * HD;
        const float* gb2 = gin_b2 + (size_t)i * HD;
        const float* fW1 = ffn_W1 + (size_t)i * HD * HD;
        const float* fb1 = ffn_b1 + (size_t)i * HD;
        const float* fW2 = ffn_W2 + (size_t)i * HD * HD;
        const float* fb2 = ffn_b2 + (size_t)i * HD;
        const float* gam = bn_gamma + (size_t)i * HD;
        const float* bet = bn_beta + (size_t)i * HD;

        // virtual node path
        hipLaunchKernelGGL(k_mean_pool, dim3(NG), dim3(HD), 0, stream, h, goff, poolb);
        launch_gemm(stream, poolb, uW1, ub1, nullptr, nullptr, tsmall, NG, HD, HD, true);
        launch_gemm(stream, tsmall, uW2, ub2, vn, nullptr, vbuf, NG, HD, H4, false);   // +vn
        launch_gemm(stream, vbuf, pW1, pb1, nullptr, nullptr, tsmall, NG, H4, HD, true);
        launch_gemm(stream, tsmall, pW2, pb2, nullptr, nullptr, outvnb, NG, HD, HD, false);

        // GIN: f2 = h + agg ; f1 = gelu(f2@W1+b1) ; f2 = f1@W2+b2 + h
        hipLaunchKernelGGL(k_agg_add, dim3(NN), dim3(HD), 0, stream, h, eoff, csr, f2);
        launch_gemm(stream, f2, gW1, gb1, nullptr, nullptr, f1, NN, HD, HD, true);
        launch_gemm(stream, f1, gW2, gb2, nullptr, h, f2, NN, HD, HD, false);

        // BatchNorm on f2 -> A(h buffer) ; B(f1) = A + outvn[batch]
        hipMemsetAsync(bnsum, 0, 2 * HD * sizeof(float), stream);
        hipLaunchKernelGGL(k_bn_stats, dim3((NN + 255) / 256), dim3(HD), 0, stream, f2, bnsum, bnsq, NN, 256);
        hipLaunchKernelGGL(k_bn_final, dim3(1), dim3(HD), 0, stream, bnsum, bnsq, gam, bet, bnscale, bnshift);
        hipLaunchKernelGGL(k_bn_apply, dim3(NN), dim3(HD), 0, stream, f2, bnscale, bnshift, outvnb, batch, h, f1);

        // FFN: f2 = gelu(f1@W1+b1) ; f1 = f2@W2+b2 + h(bn'd)
        launch_gemm(stream, f1, fW1, fb1, nullptr, nullptr, f2, NN, HD, HD, true);
        launch_gemm(stream, f2, fW2, fb2, nullptr, h, f1, NN, HD, HD, false);

        // rotate: new h = f1
        float* oldh = h;
        h = f1;
        f1 = f2;
        f2 = oldh;
    }

    // post: out = ffnn(mean_pool(h))
    hipLaunchKernelGGL(k_mean_pool, dim3(NG), dim3(HD), 0, stream, h, goff, poolb);
    launch_gemm(stream, poolb, post_W1, post_b1, nullptr, nullptr, tsmall, NG, HD, HD, true);
    launch_gemm(stream, tsmall, post_W2, post_b2, nullptr, nullptr, out, NG, HD, DOUT, false);
}

// Round 2
// 2784.940 us; speedup vs baseline: 1.5945x; 1.5945x over previous
//
#include <hip/hip_runtime.h>
#include <hip/hip_bf16.h>
#include <math.h>

#define NN 50000
#define NNP 50048          // padded to multiple of 128
#define NE 800000
#define NG 512
#define DIN 128
#define HD 256
#define DOUT 128
#define NL 5
#define H4 1024

typedef _Float16 f16x8 __attribute__((ext_vector_type(8)));
typedef _Float16 f16x4 __attribute__((ext_vector_type(4)));
typedef float f32x4 __attribute__((ext_vector_type(4)));

__device__ __forceinline__ float gelu_exact(float x) {
    return 0.5f * x * (1.0f + erff(x * 0.70710678118654752f));
}

__device__ __forceinline__ void gl_lds16(const _Float16* g, _Float16* l) {
    __builtin_amdgcn_global_load_lds(
        (const __attribute__((address_space(1))) unsigned int*)g,
        (__attribute__((address_space(3))) unsigned int*)l, 16, 0, 0);
}

// ---------------- graph meta ----------------
__global__ void k_hist(const int* __restrict__ idx, int* __restrict__ cnt, int n) {
    int i = blockIdx.x * blockDim.x + threadIdx.x;
    if (i < n) atomicAdd(&cnt[idx[i]], 1);
}

__global__ void k_scan_excl(const int* __restrict__ in, int* __restrict__ out, int n) {
    __shared__ int buf[1024];
    __shared__ int carry_s;
    int tid = threadIdx.x;
    if (tid == 0) carry_s = 0;
    __syncthreads();
    for (int base = 0; base < n; base += 1024) {
        int i = base + tid;
        int v = (i < n) ? in[i] : 0;
        buf[tid] = v;
        __syncthreads();
        for (int off = 1; off < 1024; off <<= 1) {
            int t = (tid >= off) ? buf[tid - off] : 0;
            __syncthreads();
            buf[tid] += t;
            __syncthreads();
        }
        int inc = buf[tid];
        int tot = buf[1023];
        int c = carry_s;
        if (i < n) out[i] = c + inc - v;
        __syncthreads();
        if (tid == 0) carry_s = c + tot;
        __syncthreads();
    }
    if (tid == 0) out[n] = carry_s;
}

__global__ void k_fill_csr(const int* __restrict__ src, const int* __restrict__ dst,
                           const int* __restrict__ eoff, int* __restrict__ cursor,
                           int* __restrict__ csr, int n) {
    int e = blockIdx.x * blockDim.x + threadIdx.x;
    if (e < n) {
        int d = dst[e];
        int p = atomicAdd(&cursor[d], 1);
        csr[eoff[d] + p] = src[e];
    }
}

// ---------------- converts ----------------
__global__ void k_cvt16(const float* __restrict__ in, _Float16* __restrict__ out, int n4) {
    int i = blockIdx.x * blockDim.x + threadIdx.x;
    if (i < n4) {
        float4 v = *(const float4*)&in[i * 4];
        f16x4 o = { (_Float16)v.x, (_Float16)v.y, (_Float16)v.z, (_Float16)v.w };
        *(f16x4*)&out[i * 4] = o;
    }
}

// transpose + convert: Wt[l][n][k] = (fp16) W[l][k][n]
__global__ void k_wt(const float* __restrict__ W, _Float16* __restrict__ Wt, int K, int N) {
    __shared__ float tile[32][33];
    size_t mat = (size_t)K * N;
    W += blockIdx.z * mat;
    Wt += blockIdx.z * mat;
    int n0 = blockIdx.x * 32, k0 = blockIdx.y * 32;
    for (int i = threadIdx.y; i < 32; i += 8)
        tile[i][threadIdx.x] = W[(size_t)(k0 + i) * N + n0 + threadIdx.x];
    __syncthreads();
    for (int i = threadIdx.y; i < 32; i += 8)
        Wt[(size_t)(n0 + i) * K + k0 + threadIdx.x] = (_Float16)tile[threadIdx.x][i];
}

// ---------------- pooling / aggregation (fp16 h) ----------------
__global__ void k_pool16(const _Float16* __restrict__ h16, const int* __restrict__ goff,
                         _Float16* __restrict__ pool) {
    int g = blockIdx.x;
    int c = threadIdx.x;
    int s = goff[g], e = goff[g + 1];
    float acc = 0.f;
    for (int r = s; r < e; ++r) acc += (float)h16[(size_t)r * HD + c];
    int cnt = e - s;
    pool[g * HD + c] = (_Float16)(acc / (float)(cnt > 0 ? cnt : 1));
}

__global__ __launch_bounds__(256) void k_agg16(const _Float16* __restrict__ h16,
                                               const int* __restrict__ eoff,
                                               const int* __restrict__ csr,
                                               _Float16* __restrict__ out) {
    int node = blockIdx.x * 4 + (threadIdx.x >> 6);
    if (node >= NN) return;
    int lane = threadIdx.x & 63;
    int s = eoff[node], e = eoff[node + 1];
    f16x4 mine = *(const f16x4*)&h16[(size_t)node * HD + lane * 4];
    float a0 = (float)mine[0], a1 = (float)mine[1], a2 = (float)mine[2], a3 = (float)mine[3];
    for (int j = s; j < e; ++j) {
        int src = csr[j];
        f16x4 v = *(const f16x4*)&h16[(size_t)src * HD + lane * 4];
        a0 += (float)v[0]; a1 += (float)v[1]; a2 += (float)v[2]; a3 += (float)v[3];
    }
    f16x4 o = { (_Float16)a0, (_Float16)a1, (_Float16)a2, (_Float16)a3 };
    *(f16x4*)&out[(size_t)node * HD + lane * 4] = o;
}

// ---------------- batch norm ----------------
__global__ void k_bn_stats(const float* __restrict__ h, float* __restrict__ s,
                           float* __restrict__ q, int rows, int rpb) {
    int c = threadIdx.x;
    int r0 = blockIdx.x * rpb;
    int r1 = min(r0 + rpb, rows);
    float a = 0.f, b = 0.f;
    for (int r = r0; r < r1; ++r) {
        float v = h[(size_t)r * HD + c];
        a += v; b += v * v;
    }
    atomicAdd(&s[c], a);
    atomicAdd(&q[c], b);
}

__global__ void k_bn_final(const float* __restrict__ s, const float* __restrict__ q,
                           const float* __restrict__ gamma, const float* __restrict__ beta,
                           float* __restrict__ scale, float* __restrict__ shift) {
    int c = threadIdx.x;
    float mu = s[c] * (1.0f / NN);
    float var = q[c] * (1.0f / NN) - mu * mu;
    float rs = rsqrtf(var + 1e-5f);
    float sc = rs * gamma[c];
    scale[c] = sc;
    shift[c] = beta[c] - mu * sc;
}

// in-place BN on f2, plus fp16 (bn(h) + outvn[batch]) for the FFN GEMM input
__global__ void k_bn_apply(const float* __restrict__ scale, const float* __restrict__ shift,
                           const float* __restrict__ outvn, const int* __restrict__ batch,
                           float* __restrict__ f2, _Float16* __restrict__ B16) {
    int n = blockIdx.x;
    int c = threadIdx.x;
    size_t i = (size_t)n * HD + c;
    float v = f2[i] * scale[c] + shift[c];
    f2[i] = v;
    B16[i] = (_Float16)(v + outvn[(size_t)batch[n] * HD + c]);
}

// ---------------- MFMA fp16 GEMM ----------------
// A: [M][K] fp16 (rows padded to >= gridDim.y*128), Wt: [N][K] fp16
// C = epi(A @ Wt^T + bias [+bias2]) [+R], stored fp32 and/or fp16
template <bool GELU, bool RES, bool BIAS2, bool O32, bool O16>
__global__ __launch_bounds__(256) void k_mgemm(const _Float16* __restrict__ A,
                                               const _Float16* __restrict__ Wt,
                                               const float* __restrict__ bias,
                                               const float* __restrict__ bias2,
                                               const float* __restrict__ R,
                                               float* __restrict__ C32,
                                               _Float16* __restrict__ C16,
                                               int M, int N, int K) {
    __shared__ _Float16 As[4][128][8];   // [kb][row][e] : A[m0+row][k0+kb*8+e]
    __shared__ _Float16 Bs[4][128][8];   // [kb][col][e] : Wt[n0+col][k0+kb*8+e]
    const int t = threadIdx.x;
    const int w = t >> 6, lane = t & 63;
    const int wr = w & 1, wc = w >> 1;
    const int m0 = blockIdx.y * 128, n0 = blockIdx.x * 128;
    const int kb = lane >> 4, fr = lane & 15;

    f32x4 acc[4][4];
#pragma unroll
    for (int mi = 0; mi < 4; ++mi)
#pragma unroll
        for (int ni = 0; ni < 4; ++ni) acc[mi][ni] = (f32x4){0.f, 0.f, 0.f, 0.f};

    // wave w stages k-block kb=w for both operands (rows lane and 64+lane)
    const _Float16* gA0 = A + (size_t)(m0 + lane) * K + w * 8;
    const _Float16* gA1 = A + (size_t)(m0 + 64 + lane) * K + w * 8;
    const _Float16* gB0 = Wt + (size_t)(n0 + lane) * K + w * 8;
    const _Float16* gB1 = Wt + (size_t)(n0 + 64 + lane) * K + w * 8;

    for (int k0 = 0; k0 < K; k0 += 32) {
        gl_lds16(gA0 + k0, &As[w][0][0]);
        gl_lds16(gA1 + k0, &As[w][64][0]);
        gl_lds16(gB0 + k0, &Bs[w][0][0]);
        gl_lds16(gB1 + k0, &Bs[w][64][0]);
        __syncthreads();
        f16x8 af[4], bf[4];
#pragma unroll
        for (int mi = 0; mi < 4; ++mi)
            af[mi] = *(const f16x8*)&As[kb][wr * 64 + mi * 16 + fr][0];
#pragma unroll
        for (int ni = 0; ni < 4; ++ni)
            bf[ni] = *(const f16x8*)&Bs[kb][wc * 64 + ni * 16 + fr][0];
#pragma unroll
        for (int mi = 0; mi < 4; ++mi)
#pragma unroll
            for (int ni = 0; ni < 4; ++ni)
                acc[mi][ni] = __builtin_amdgcn_mfma_f32_16x16x32_f16(af[mi], bf[ni], acc[mi][ni], 0, 0, 0);
        __syncthreads();
    }

    const int rr = lane >> 4;
#pragma unroll
    for (int mi = 0; mi < 4; ++mi) {
#pragma unroll
        for (int reg = 0; reg < 4; ++reg) {
            int m = m0 + wr * 64 + mi * 16 + rr * 4 + reg;
            if (m < M) {
#pragma unroll
                for (int ni = 0; ni < 4; ++ni) {
                    int n = n0 + wc * 64 + ni * 16 + fr;
                    float v = acc[mi][ni][reg] + bias[n];
                    if (BIAS2) v += bias2[n];
                    if (GELU) v = gelu_exact(v);
                    if (RES) v += R[(size_t)m * N + n];
                    if (O32) C32[(size_t)m * N + n] = v;
                    if (O16) C16[(size_t)m * N + n] = (_Float16)v;
                }
            }
        }
    }
}

static inline void mgemm(hipStream_t st, const _Float16* A, const _Float16* Wt,
                         const float* bias, const float* bias2, const float* R,
                         float* C32, _Float16* C16, int M, int N, int K, bool gelu) {
    dim3 g(N / 128, (M + 127) / 128), b(256);
    if (gelu)
        k_mgemm<true, false, false, false, true><<<g, b, 0, st>>>(A, Wt, bias, nullptr, nullptr, nullptr, C16, M, N, K);
    else if (R && C16)
        k_mgemm<false, true, false, true, true><<<g, b, 0, st>>>(A, Wt, bias, nullptr, R, C32, C16, M, N, K);
    else if (R)
        k_mgemm<false, true, false, true, false><<<g, b, 0, st>>>(A, Wt, bias, nullptr, R, C32, nullptr, M, N, K);
    else if (bias2)
        k_mgemm<false, false, true, false, true><<<g, b, 0, st>>>(A, Wt, bias, bias2, nullptr, nullptr, C16, M, N, K);
    else if (C16)
        k_mgemm<false, false, false, true, true><<<g, b, 0, st>>>(A, Wt, bias, nullptr, nullptr, C32, C16, M, N, K);
    else
        k_mgemm<false, false, false, true, false><<<g, b, 0, st>>>(A, Wt, bias, nullptr, nullptr, C32, nullptr, M, N, K);
}

extern "C" void kernel_launch(void* const* d_in, const int* in_sizes, int n_in,
                              void* d_out, int out_size, void* d_ws, size_t ws_size,
                              hipStream_t stream) {
    const float* x       = (const float*)d_in[0];
    const int*   ei      = (const int*)d_in[1];
    const int*   batch   = (const int*)d_in[2];
    const float* pre_W1  = (const float*)d_in[3];
    const float* pre_b1  = (const float*)d_in[4];
    const float* pre_W2  = (const float*)d_in[5];
    const float* pre_b2  = (const float*)d_in[6];
    const float* gin_W1  = (const float*)d_in[7];
    const float* gin_b1  = (const float*)d_in[8];
    const float* gin_W2  = (const float*)d_in[9];
    const float* gin_b2  = (const float*)d_in[10];
    const float* ffn_W1  = (const float*)d_in[11];
    const float* ffn_b1  = (const float*)d_in[12];
    const float* ffn_W2  = (const float*)d_in[13];
    const float* ffn_b2  = (const float*)d_in[14];
    const float* upd_W1  = (const float*)d_in[15];
    const float* upd_b1  = (const float*)d_in[16];
    const float* upd_W2  = (const float*)d_in[17];
    const float* upd_b2  = (const float*)d_in[18];
    const float* prop_W1 = (const float*)d_in[19];
    const float* prop_b1 = (const float*)d_in[20];
    const float* prop_W2 = (const float*)d_in[21];
    const float* prop_b2 = (const float*)d_in[22];
    const float* bn_gamma= (const float*)d_in[23];
    const float* bn_beta = (const float*)d_in[24];
    const float* vn      = (const float*)d_in[25];
    const float* post_W1 = (const float*)d_in[26];
    const float* post_b1 = (const float*)d_in[27];
    const float* post_W2 = (const float*)d_in[28];
    const float* post_b2 = (const float*)d_in[29];
    float* out = (float*)d_out;

    const int* e_src = ei;
    const int* e_dst = ei + NE;

    // ---------- workspace layout ----------
    char* p = (char*)d_ws;
    auto alloc = [&](size_t bytes) -> char* {
        char* r = p;
        p += (bytes + 255) & ~(size_t)255;
        return r;
    };
    float*    B32a   = (float*)alloc((size_t)NNP * HD * 4);   // h32 / ffn2 out
    float*    B32b   = (float*)alloc((size_t)NNP * HD * 4);   // gin2 out / bn'd h
    _Float16* h16    = (_Float16*)alloc((size_t)NNP * HD * 2);
    _Float16* t16a   = (_Float16*)alloc((size_t)NNP * HD * 2);
    _Float16* t16b   = (_Float16*)alloc((size_t)NNP * HD * 2); // also aliases x16
    _Float16* pool16 = (_Float16*)alloc((size_t)NG * HD * 2);
    _Float16* u16    = (_Float16*)alloc((size_t)NG * HD * 2);
    _Float16* vb16   = (_Float16*)alloc((size_t)NG * H4 * 2);
    _Float16* p16    = (_Float16*)alloc((size_t)NG * HD * 2);
    float*    outvn32= (float*)alloc((size_t)NG * HD * 4);
    float*    bnsum  = (float*)alloc(HD * 4);
    float*    bnsq   = (float*)alloc(HD * 4);
    float*    bnscale= (float*)alloc(HD * 4);
    float*    bnshift= (float*)alloc(HD * 4);
    _Float16* preW1t = (_Float16*)alloc((size_t)HD * DIN * 2);
    _Float16* preW2t = (_Float16*)alloc((size_t)HD * HD * 2);
    _Float16* ginW1t = (_Float16*)alloc((size_t)NL * HD * HD * 2);
    _Float16* ginW2t = (_Float16*)alloc((size_t)NL * HD * HD * 2);
    _Float16* ffnW1t = (_Float16*)alloc((size_t)NL * HD * HD * 2);
    _Float16* ffnW2t = (_Float16*)alloc((size_t)NL * HD * HD * 2);
    _Float16* updW1t = (_Float16*)alloc((size_t)NL * HD * HD * 2);
    _Float16* updW2t = (_Float16*)alloc((size_t)NL * HD * H4 * 2);
    _Float16* propW1t= (_Float16*)alloc((size_t)NL * H4 * HD * 2);
    _Float16* propW2t= (_Float16*)alloc((size_t)NL * HD * HD * 2);
    _Float16* postW1t= (_Float16*)alloc((size_t)HD * HD * 2);
    _Float16* postW2t= (_Float16*)alloc((size_t)DOUT * HD * 2);
    int* gcount = (int*)alloc(NG * 4);
    int* goff   = (int*)alloc((NG + 1) * 4);
    int* deg    = (int*)alloc(NN * 4);
    int* eoff   = (int*)alloc((NN + 1) * 4);
    int* cursor = (int*)alloc(NN * 4);
    int* csr    = (int*)alloc((size_t)NE * 4);
    _Float16* x16 = t16b;  // alias: only live before pre-GEMM1

    // ---------- graph meta ----------
    hipMemsetAsync(gcount, 0, NG * 4, stream);
    hipMemsetAsync(deg, 0, NN * 4, stream);
    hipMemsetAsync(cursor, 0, NN * 4, stream);
    hipLaunchKernelGGL(k_hist, dim3((NN + 255) / 256), dim3(256), 0, stream, batch, gcount, NN);
    hipLaunchKernelGGL(k_hist, dim3((NE + 255) / 256), dim3(256), 0, stream, e_dst, deg, NE);
    hipLaunchKernelGGL(k_scan_excl, dim3(1), dim3(1024), 0, stream, gcount, goff, NG);
    hipLaunchKernelGGL(k_scan_excl, dim3(1), dim3(1024), 0, stream, deg, eoff, NN);
    hipLaunchKernelGGL(k_fill_csr, dim3((NE + 255) / 256), dim3(256), 0, stream, e_src, e_dst, eoff, cursor, csr, NE);

    // ---------- weight convert + transpose ----------
    dim3 tb(32, 8);
    hipLaunchKernelGGL(k_wt, dim3(HD / 32, DIN / 32, 1), tb, 0, stream, pre_W1, preW1t, DIN, HD);
    hipLaunchKernelGGL(k_wt, dim3(HD / 32, HD / 32, 1), tb, 0, stream, pre_W2, preW2t, HD, HD);
    hipLaunchKernelGGL(k_wt, dim3(HD / 32, HD / 32, NL), tb, 0, stream, gin_W1, ginW1t, HD, HD);
    hipLaunchKernelGGL(k_wt, dim3(HD / 32, HD / 32, NL), tb, 0, stream, gin_W2, ginW2t, HD, HD);
    hipLaunchKernelGGL(k_wt, dim3(HD / 32, HD / 32, NL), tb, 0, stream, ffn_W1, ffnW1t, HD, HD);
    hipLaunchKernelGGL(k_wt, dim3(HD / 32, HD / 32, NL), tb, 0, stream, ffn_W2, ffnW2t, HD, HD);
    hipLaunchKernelGGL(k_wt, dim3(HD / 32, HD / 32, NL), tb, 0, stream, upd_W1, updW1t, HD, HD);
    hipLaunchKernelGGL(k_wt, dim3(H4 / 32, HD / 32, NL), tb, 0, stream, upd_W2, updW2t, HD, H4);
    hipLaunchKernelGGL(k_wt, dim3(HD / 32, H4 / 32, NL), tb, 0, stream, prop_W1, propW1t, H4, HD);
    hipLaunchKernelGGL(k_wt, dim3(HD / 32, HD / 32, NL), tb, 0, stream, prop_W2, propW2t, HD, HD);
    hipLaunchKernelGGL(k_wt, dim3(HD / 32, HD / 32, 1), tb, 0, stream, post_W1, postW1t, HD, HD);
    hipLaunchKernelGGL(k_wt, dim3(DOUT / 32, HD / 32, 1), tb, 0, stream, post_W2, postW2t, HD, DOUT);

    // x -> fp16
    int n4 = NN * DIN / 4;
    hipLaunchKernelGGL(k_cvt16, dim3((n4 + 255) / 256), dim3(256), 0, stream, x, x16, n4);

    // ---------- pre-FFNN ----------
    mgemm(stream, x16, preW1t, pre_b1, nullptr, nullptr, nullptr, t16a, NN, HD, DIN, true);
    mgemm(stream, t16a, preW2t, pre_b2, nullptr, nullptr, B32a, h16, NN, HD, HD, false);

    for (int i = 0; i < NL; ++i) {
        const _Float16* uW1 = updW1t + (size_t)i * HD * HD;
        const _Float16* uW2 = updW2t + (size_t)i * HD * H4;
        const _Float16* pW1 = propW1t + (size_t)i * H4 * HD;
        const _Float16* pW2 = propW2t + (size_t)i * HD * HD;
        const _Float16* gW1 = ginW1t + (size_t)i * HD * HD;
        const _Float16* gW2 = ginW2t + (size_t)i * HD * HD;
        const _Float16* fW1 = ffnW1t + (size_t)i * HD * HD;
        const _Float16* fW2 = ffnW2t + (size_t)i * HD * HD;

        // virtual-node path
        hipLaunchKernelGGL(k_pool16, dim3(NG), dim3(HD), 0, stream, h16, goff, pool16);
        mgemm(stream, pool16, uW1, upd_b1 + (size_t)i * HD, nullptr, nullptr, nullptr, u16, NG, HD, HD, true);
        mgemm(stream, u16, uW2, upd_b2 + (size_t)i * H4, vn, nullptr, nullptr, vb16, NG, H4, HD, false);
        mgemm(stream, vb16, pW1, prop_b1 + (size_t)i * HD, nullptr, nullptr, nullptr, p16, NG, HD, H4, true);
        mgemm(stream, p16, pW2, prop_b2 + (size_t)i * HD, nullptr, nullptr, outvn32, nullptr, NG, HD, HD, false);

        // GIN
        hipLaunchKernelGGL(k_agg16, dim3(NN / 4), dim3(256), 0, stream, h16, eoff, csr, t16a);
        mgemm(stream, t16a, gW1, gin_b1 + (size_t)i * HD, nullptr, nullptr, nullptr, t16b, NN, HD, HD, true);
        mgemm(stream, t16b, gW2, gin_b2 + (size_t)i * HD, nullptr, B32a, B32b, nullptr, NN, HD, HD, false);

        // BatchNorm (in-place on B32b) + fp16 FFN input (t16a)
        hipMemsetAsync(bnsum, 0, HD * 4, stream);
        hipMemsetAsync(bnsq, 0, HD * 4, stream);
        hipLaunchKernelGGL(k_bn_stats, dim3((NN + 255) / 256), dim3(HD), 0, stream, B32b, bnsum, bnsq, NN, 256);
        hipLaunchKernelGGL(k_bn_final, dim3(1), dim3(HD), 0, stream, bnsum, bnsq,
                           bn_gamma + (size_t)i * HD, bn_beta + (size_t)i * HD, bnscale, bnshift);
        hipLaunchKernelGGL(k_bn_apply, dim3(NN), dim3(HD), 0, stream, bnscale, bnshift, outvn32, batch, B32b, t16a);

        // FFN
        mgemm(stream, t16a, fW1, ffn_b1 + (size_t)i * HD, nullptr, nullptr, nullptr, t16b, NN, HD, HD, true);
        mgemm(stream, t16b, fW2, ffn_b2 + (size_t)i * HD, nullptr, B32b, B32a, h16, NN, HD, HD, false);
    }

    // ---------- post ----------
    hipLaunchKernelGGL(k_pool16, dim3(NG), dim3(HD), 0, stream, h16, goff, pool16);
    mgemm(stream, pool16, postW1t, post_b1, nullptr, nullptr, nullptr, u16, NG, HD, HD, true);
    mgemm(stream, u16, postW2t, post_b2, nullptr, nullptr, out, nullptr, NG, DOUT, HD, false);
}

// Round 5
// 2290.382 us; speedup vs baseline: 1.9388x; 1.2159x over previous
//
#include <hip/hip_runtime.h>
#include <hip/hip_bf16.h>
#include <math.h>

#define NN 50000
#define NNP 50048          // padded to multiple of 128
#define NE 800000
#define NG 512
#define DIN 128
#define HD 256
#define DOUT 128
#define NL 5
#define H4 1024

typedef _Float16 f16x8 __attribute__((ext_vector_type(8)));
typedef _Float16 f16x4 __attribute__((ext_vector_type(4)));
typedef float f32x4 __attribute__((ext_vector_type(4)));

__device__ __forceinline__ float gelu_exact(float x) {
    return 0.5f * x * (1.0f + erff(x * 0.70710678118654752f));
}

__device__ __forceinline__ void gl_lds16(const _Float16* g, _Float16* l) {
    __builtin_amdgcn_global_load_lds(
        (const __attribute__((address_space(1))) unsigned int*)g,
        (__attribute__((address_space(3))) unsigned int*)l, 16, 0, 0);
}

// ---------------- graph meta ----------------
__global__ void k_hist(const int* __restrict__ idx, int* __restrict__ cnt, int n) {
    int i = blockIdx.x * blockDim.x + threadIdx.x;
    if (i < n) atomicAdd(&cnt[idx[i]], 1);
}

__global__ void k_scan_part(const int* __restrict__ in, int* __restrict__ bsum, int n) {
    __shared__ int buf[256];
    int i = blockIdx.x * 256 + threadIdx.x;
    buf[threadIdx.x] = (i < n) ? in[i] : 0;
    __syncthreads();
    for (int off = 128; off > 0; off >>= 1) {
        if (threadIdx.x < off) buf[threadIdx.x] += buf[threadIdx.x + off];
        __syncthreads();
    }
    if (threadIdx.x == 0) bsum[blockIdx.x] = buf[0];
}

// single block: exclusive scan of nb block sums (nb<=1024); also writes out[n]=total
__global__ void k_scan_mid(const int* __restrict__ bsum, int* __restrict__ bexcl, int nb,
                           int* __restrict__ out, int n) {
    __shared__ int buf[1024];
    int t = threadIdx.x;
    int v = (t < nb) ? bsum[t] : 0;
    buf[t] = v;
    __syncthreads();
    for (int off = 1; off < 1024; off <<= 1) {
        int x = (t >= off) ? buf[t - off] : 0;
        __syncthreads();
        buf[t] += x;
        __syncthreads();
    }
    if (t < nb) bexcl[t] = buf[t] - v;
    if (t == 1023) out[n] = buf[1023];
}

__global__ void k_scan_out(const int* __restrict__ in, const int* __restrict__ bexcl,
                           int* __restrict__ out, int n) {
    __shared__ int buf[256];
    int i = blockIdx.x * 256 + threadIdx.x;
    int t = threadIdx.x;
    int v = (i < n) ? in[i] : 0;
    buf[t] = v;
    __syncthreads();
    for (int off = 1; off < 256; off <<= 1) {
        int x = (t >= off) ? buf[t - off] : 0;
        __syncthreads();
        buf[t] += x;
        __syncthreads();
    }
    if (i < n) out[i] = bexcl[blockIdx.x] + buf[t] - v;
}

__global__ void k_fill_csr(const int* __restrict__ src, const int* __restrict__ dst,
                           const int* __restrict__ eoff, int* __restrict__ cursor,
                           int* __restrict__ csr, int n) {
    int e = blockIdx.x * blockDim.x + threadIdx.x;
    if (e < n) {
        int d = dst[e];
        int p = atomicAdd(&cursor[d], 1);
        csr[eoff[d] + p] = src[e];
    }
}

// ---------------- converts ----------------
__global__ void k_cvt16(const float* __restrict__ in, _Float16* __restrict__ out, int n4) {
    int i = blockIdx.x * blockDim.x + threadIdx.x;
    if (i < n4) {
        float4 v = *(const float4*)&in[i * 4];
        f16x4 o = { (_Float16)v.x, (_Float16)v.y, (_Float16)v.z, (_Float16)v.w };
        *(f16x4*)&out[i * 4] = o;
    }
}

// transpose + convert: Wt[l][n][k] = (fp16) W[l][k][n]
__global__ void k_wt(const float* __restrict__ W, _Float16* __restrict__ Wt, int K, int N) {
    __shared__ float tile[32][33];
    size_t mat = (size_t)K * N;
    W += blockIdx.z * mat;
    Wt += blockIdx.z * mat;
    int n0 = blockIdx.x * 32, k0 = blockIdx.y * 32;
    for (int i = threadIdx.y; i < 32; i += 8)
        tile[i][threadIdx.x] = W[(size_t)(k0 + i) * N + n0 + threadIdx.x];
    __syncthreads();
    for (int i = threadIdx.y; i < 32; i += 8)
        Wt[(size_t)(n0 + i) * K + k0 + threadIdx.x] = (_Float16)tile[threadIdx.x][i];
}

// ---------------- pooling / aggregation ----------------
__global__ void k_pool16(const _Float16* __restrict__ h16, const int* __restrict__ goff,
                         _Float16* __restrict__ pool) {
    int g = blockIdx.x;
    int c = threadIdx.x;
    int s = goff[g], e = goff[g + 1];
    float acc = 0.f;
    for (int r = s; r < e; ++r) acc += (float)h16[(size_t)r * HD + c];
    int cnt = e - s;
    pool[g * HD + c] = (_Float16)(acc / (float)(cnt > 0 ? cnt : 1));
}

// one wave per node; 32 lanes x f16x8 cover the 256-col row. Half-waves take
// even/odd edges, but with WAVE-UNIFORM loop bounds (jj sequence identical in
// both halves; per-half element = jj+half, guarded). __shfl always executes
// with the full wave active.
__global__ __launch_bounds__(256) void k_agg16(const _Float16* __restrict__ h16,
                                               const int* __restrict__ eoff,
                                               const int* __restrict__ csr,
                                               _Float16* __restrict__ out) {
    int node = blockIdx.x * 4 + (threadIdx.x >> 6);
    int lane = threadIdx.x & 63;
    int half = lane >> 5, l = lane & 31;
    f16x8 mine = *(const f16x8*)&h16[(size_t)node * HD + l * 8];
    float acc[8];
#pragma unroll
    for (int q = 0; q < 8; ++q) acc[q] = half ? 0.f : (float)mine[q];
    int s = eoff[node], e = eoff[node + 1];
    for (int base = s; base < e; base += 64) {
        int myi = base + lane;
        int vidx = (myi < e) ? csr[myi] : 0;
        int cnt = min(64, e - base);
        int jj = 0;
        for (; jj + 3 < cnt; jj += 4) {          // uniform: both halves fully valid
            int s0 = __shfl(vidx, jj + half);
            int s1 = __shfl(vidx, jj + 2 + half);
            f16x8 v0 = *(const f16x8*)&h16[(size_t)s0 * HD + l * 8];
            f16x8 v1 = *(const f16x8*)&h16[(size_t)s1 * HD + l * 8];
#pragma unroll
            for (int q = 0; q < 8; ++q) acc[q] += (float)v0[q] + (float)v1[q];
        }
        for (; jj < cnt; jj += 2) {              // uniform loop, predicated add
            int i0 = jj + half;
            int s0 = __shfl(vidx, i0);
            if (i0 < cnt) {
                f16x8 v0 = *(const f16x8*)&h16[(size_t)s0 * HD + l * 8];
#pragma unroll
                for (int q = 0; q < 8; ++q) acc[q] += (float)v0[q];
            }
        }
    }
#pragma unroll
    for (int q = 0; q < 8; ++q) acc[q] += __shfl_xor(acc[q], 32);
    if (!half) {
        f16x8 o;
#pragma unroll
        for (int q = 0; q < 8; ++q) o[q] = (_Float16)acc[q];
        *(f16x8*)&out[(size_t)node * HD + l * 8] = o;
    }
}

// ---------------- batch norm (fp32 tensors, fp32 stats) ----------------
__global__ __launch_bounds__(256) void k_bn_stats32(const float* __restrict__ h,
                                                    float* __restrict__ stat) {
    __shared__ float red[4][256];
    int t = threadIdx.x;
    int cg = t & 63, rg = t >> 6;
    int r0 = blockIdx.x * 256 + rg;
    int r1 = min(blockIdx.x * 256 + 256, NN);
    float a[4] = {0, 0, 0, 0}, q[4] = {0, 0, 0, 0};
    for (int r = r0; r < r1; r += 4) {
        float4 v = *(const float4*)&h[(size_t)r * HD + cg * 4];
        a[0] += v.x; a[1] += v.y; a[2] += v.z; a[3] += v.w;
        q[0] += v.x * v.x; q[1] += v.y * v.y; q[2] += v.z * v.z; q[3] += v.w * v.w;
    }
#pragma unroll
    for (int j = 0; j < 4; ++j) red[rg][cg * 4 + j] = a[j];
    __syncthreads();
    float s = red[0][t] + red[1][t] + red[2][t] + red[3][t];
    atomicAdd(&stat[t], s);
    __syncthreads();
#pragma unroll
    for (int j = 0; j < 4; ++j) red[rg][cg * 4 + j] = q[j];
    __syncthreads();
    float s2 = red[0][t] + red[1][t] + red[2][t] + red[3][t];
    atomicAdd(&stat[HD + t], s2);
}

__global__ void k_bn_final(const float* __restrict__ stat,
                           const float* __restrict__ gamma, const float* __restrict__ beta,
                           float* __restrict__ scale, float* __restrict__ shift) {
    int c = threadIdx.x;
    float mu = stat[c] * (1.0f / NN);
    float var = stat[HD + c] * (1.0f / NN) - mu * mu;
    float rs = rsqrtf(var + 1e-5f);
    float sc = rs * gamma[c];
    scale[c] = sc;
    shift[c] = beta[c] - mu * sc;
}

// in-place BN on g2 (fp32), plus fp16 (bn(g2) + outvn[batch]) FFN input
__global__ __launch_bounds__(256) void k_bn_apply32(float* __restrict__ g2,
                                                    const float* __restrict__ scale,
                                                    const float* __restrict__ shift,
                                                    const float* __restrict__ outvn,
                                                    const int* __restrict__ batch,
                                                    _Float16* __restrict__ ffin) {
    int chunk = blockIdx.x * 256 + threadIdx.x;  // 4 floats each
    if (chunk >= NN * 64) return;
    int node = chunk >> 6, cg = chunk & 63;
    float4 v = *(const float4*)&g2[(size_t)chunk * 4];
    int b = batch[node];
    float4 sc = *(const float4*)&scale[cg * 4];
    float4 sh = *(const float4*)&shift[cg * 4];
    float4 ov = *(const float4*)&outvn[(size_t)b * HD + cg * 4];
    float4 o;
    o.x = v.x * sc.x + sh.x;
    o.y = v.y * sc.y + sh.y;
    o.z = v.z * sc.z + sh.z;
    o.w = v.w * sc.w + sh.w;
    *(float4*)&g2[(size_t)chunk * 4] = o;
    f16x4 f = { (_Float16)(o.x + ov.x), (_Float16)(o.y + ov.y),
                (_Float16)(o.z + ov.z), (_Float16)(o.w + ov.w) };
    *(f16x4*)&ffin[(size_t)chunk * 4] = f;
}

// ---------------- MFMA fp16 GEMM (128x128 tile, double-buffered) ----------------
// R (residual) fp32; bias2 fp32 broadcast; C32/C16 outputs optional
template <bool GELU, bool RES, bool BIAS2, bool O32, bool O16>
__global__ __launch_bounds__(256) void k_mgemm(const _Float16* __restrict__ A,
                                               const _Float16* __restrict__ Wt,
                                               const float* __restrict__ bias,
                                               const float* __restrict__ bias2,
                                               const float* __restrict__ R,
                                               float* __restrict__ C32,
                                               _Float16* __restrict__ C16,
                                               int M, int N, int K) {
    __shared__ _Float16 As[2][4][128][8];
    __shared__ _Float16 Bs[2][4][128][8];
    const int t = threadIdx.x;
    const int w = t >> 6, lane = t & 63;
    const int wr = w & 1, wc = w >> 1;
    const int m0 = blockIdx.y * 128, n0 = blockIdx.x * 128;
    const int kb = lane >> 4, fr = lane & 15;

    f32x4 acc[4][4];
#pragma unroll
    for (int mi = 0; mi < 4; ++mi)
#pragma unroll
        for (int ni = 0; ni < 4; ++ni) acc[mi][ni] = (f32x4){0.f, 0.f, 0.f, 0.f};

    const _Float16* gA0 = A + (size_t)(m0 + lane) * K + w * 8;
    const _Float16* gA1 = A + (size_t)(m0 + 64 + lane) * K + w * 8;
    const _Float16* gB0 = Wt + (size_t)(n0 + lane) * K + w * 8;
    const _Float16* gB1 = Wt + (size_t)(n0 + 64 + lane) * K + w * 8;

    const int nt = K >> 5;
    gl_lds16(gA0, &As[0][w][0][0]);
    gl_lds16(gA1, &As[0][w][64][0]);
    gl_lds16(gB0, &Bs[0][w][0][0]);
    gl_lds16(gB1, &Bs[0][w][64][0]);
    __syncthreads();
    for (int tt = 0; tt < nt; ++tt) {
        const int cur = tt & 1;
        if (tt + 1 < nt) {
            int k0 = (tt + 1) << 5;
            gl_lds16(gA0 + k0, &As[cur ^ 1][w][0][0]);
            gl_lds16(gA1 + k0, &As[cur ^ 1][w][64][0]);
            gl_lds16(gB0 + k0, &Bs[cur ^ 1][w][0][0]);
            gl_lds16(gB1 + k0, &Bs[cur ^ 1][w][64][0]);
        }
        f16x8 af[4], bf[4];
#pragma unroll
        for (int mi = 0; mi < 4; ++mi)
            af[mi] = *(const f16x8*)&As[cur][kb][wr * 64 + mi * 16 + fr][0];
#pragma unroll
        for (int ni = 0; ni < 4; ++ni)
            bf[ni] = *(const f16x8*)&Bs[cur][kb][wc * 64 + ni * 16 + fr][0];
#pragma unroll
        for (int mi = 0; mi < 4; ++mi)
#pragma unroll
            for (int ni = 0; ni < 4; ++ni)
                acc[mi][ni] = __builtin_amdgcn_mfma_f32_16x16x32_f16(af[mi], bf[ni], acc[mi][ni], 0, 0, 0);
        __syncthreads();
    }

    const int rr = lane >> 4;
#pragma unroll
    for (int mi = 0; mi < 4; ++mi) {
#pragma unroll
        for (int reg = 0; reg < 4; ++reg) {
            int m = m0 + wr * 64 + mi * 16 + rr * 4 + reg;
            if (m < M) {
#pragma unroll
                for (int ni = 0; ni < 4; ++ni) {
                    int n = n0 + wc * 64 + ni * 16 + fr;
                    float v = acc[mi][ni][reg] + bias[n];
                    if (BIAS2) v += bias2[n];
                    if (GELU) v = gelu_exact(v);
                    if (RES) v += R[(size_t)m * N + n];
                    if (O32) C32[(size_t)m * N + n] = v;
                    if (O16) C16[(size_t)m * N + n] = (_Float16)v;
                }
            }
        }
    }
}

// helpers
static inline void mg_gelu(hipStream_t st, const _Float16* A, const _Float16* Wt,
                           const float* bias, _Float16* C16, int M, int N, int K) {
    dim3 g(N / 128, (M + 127) / 128), b(256);
    k_mgemm<true, false, false, false, true><<<g, b, 0, st>>>(A, Wt, bias, nullptr, nullptr, nullptr, C16, M, N, K);
}
static inline void mg_both(hipStream_t st, const _Float16* A, const _Float16* Wt,
                           const float* bias, float* C32, _Float16* C16, int M, int N, int K) {
    dim3 g(N / 128, (M + 127) / 128), b(256);
    k_mgemm<false, false, false, true, true><<<g, b, 0, st>>>(A, Wt, bias, nullptr, nullptr, C32, C16, M, N, K);
}
static inline void mg_res32(hipStream_t st, const _Float16* A, const _Float16* Wt,
                            const float* bias, const float* R, float* C32, int M, int N, int K) {
    dim3 g(N / 128, (M + 127) / 128), b(256);
    k_mgemm<false, true, false, true, false><<<g, b, 0, st>>>(A, Wt, bias, nullptr, R, C32, nullptr, M, N, K);
}
static inline void mg_res_both(hipStream_t st, const _Float16* A, const _Float16* Wt,
                               const float* bias, const float* R, float* C32, _Float16* C16,
                               int M, int N, int K) {
    dim3 g(N / 128, (M + 127) / 128), b(256);
    k_mgemm<false, true, false, true, true><<<g, b, 0, st>>>(A, Wt, bias, nullptr, R, C32, C16, M, N, K);
}
static inline void mg_bias2_16(hipStream_t st, const _Float16* A, const _Float16* Wt,
                               const float* bias, const float* bias2, _Float16* C16,
                               int M, int N, int K) {
    dim3 g(N / 128, (M + 127) / 128), b(256);
    k_mgemm<false, false, true, false, true><<<g, b, 0, st>>>(A, Wt, bias, bias2, nullptr, nullptr, C16, M, N, K);
}
static inline void mg_f32only(hipStream_t st, const _Float16* A, const _Float16* Wt,
                              const float* bias, float* C32, int M, int N, int K) {
    dim3 g(N / 128, (M + 127) / 128), b(256);
    k_mgemm<false, false, false, true, false><<<g, b, 0, st>>>(A, Wt, bias, nullptr, nullptr, C32, nullptr, M, N, K);
}

extern "C" void kernel_launch(void* const* d_in, const int* in_sizes, int n_in,
                              void* d_out, int out_size, void* d_ws, size_t ws_size,
                              hipStream_t stream) {
    const float* x       = (const float*)d_in[0];
    const int*   ei      = (const int*)d_in[1];
    const int*   batch   = (const int*)d_in[2];
    const float* pre_W1  = (const float*)d_in[3];
    const float* pre_b1  = (const float*)d_in[4];
    const float* pre_W2  = (const float*)d_in[5];
    const float* pre_b2  = (const float*)d_in[6];
    const float* gin_W1  = (const float*)d_in[7];
    const float* gin_b1  = (const float*)d_in[8];
    const float* gin_W2  = (const float*)d_in[9];
    const float* gin_b2  = (const float*)d_in[10];
    const float* ffn_W1  = (const float*)d_in[11];
    const float* ffn_b1  = (const float*)d_in[12];
    const float* ffn_W2  = (const float*)d_in[13];
    const float* ffn_b2  = (const float*)d_in[14];
    const float* upd_W1  = (const float*)d_in[15];
    const float* upd_b1  = (const float*)d_in[16];
    const float* upd_W2  = (const float*)d_in[17];
    const float* upd_b2  = (const float*)d_in[18];
    const float* prop_W1 = (const float*)d_in[19];
    const float* prop_b1 = (const float*)d_in[20];
    const float* prop_W2 = (const float*)d_in[21];
    const float* prop_b2 = (const float*)d_in[22];
    const float* bn_gamma= (const float*)d_in[23];
    const float* bn_beta = (const float*)d_in[24];
    const float* vn      = (const float*)d_in[25];
    const float* post_W1 = (const float*)d_in[26];
    const float* post_b1 = (const float*)d_in[27];
    const float* post_W2 = (const float*)d_in[28];
    const float* post_b2 = (const float*)d_in[29];
    float* out = (float*)d_out;

    const int* e_src = ei;
    const int* e_dst = ei + NE;

    // ---------- workspace layout ----------
    char* p = (char*)d_ws;
    auto alloc = [&](size_t bytes) -> char* {
        char* r = p;
        p += (bytes + 255) & ~(size_t)255;
        return r;
    };
    float*    h32    = (float*)alloc((size_t)NNP * HD * 4);   // fp32 backbone
    float*    g32    = (float*)alloc((size_t)NNP * HD * 4);   // gin2 out -> bn'd (in-place)
    _Float16* h16    = (_Float16*)alloc((size_t)NNP * HD * 2);
    _Float16* t16a   = (_Float16*)alloc((size_t)NNP * HD * 2);
    _Float16* t16b   = (_Float16*)alloc((size_t)NNP * HD * 2);  // aliases x16 pre-launch
    _Float16* pool16 = (_Float16*)alloc((size_t)NG * HD * 2);
    _Float16* u16    = (_Float16*)alloc((size_t)NG * HD * 2);
    _Float16* vb16   = (_Float16*)alloc((size_t)NG * H4 * 2);
    _Float16* p16    = (_Float16*)alloc((size_t)NG * HD * 2);
    float*    outvn32= (float*)alloc((size_t)NG * HD * 4);
    float*    bnstat = (float*)alloc(2 * HD * 4);
    float*    bnscale= (float*)alloc(HD * 4);
    float*    bnshift= (float*)alloc(HD * 4);
    _Float16* preW1t = (_Float16*)alloc((size_t)HD * DIN * 2);
    _Float16* preW2t = (_Float16*)alloc((size_t)HD * HD * 2);
    _Float16* ginW1t = (_Float16*)alloc((size_t)NL * HD * HD * 2);
    _Float16* ginW2t = (_Float16*)alloc((size_t)NL * HD * HD * 2);
    _Float16* ffnW1t = (_Float16*)alloc((size_t)NL * HD * HD * 2);
    _Float16* ffnW2t = (_Float16*)alloc((size_t)NL * HD * HD * 2);
    _Float16* updW1t = (_Float16*)alloc((size_t)NL * HD * HD * 2);
    _Float16* updW2t = (_Float16*)alloc((size_t)NL * HD * H4 * 2);
    _Float16* propW1t= (_Float16*)alloc((size_t)NL * H4 * HD * 2);
    _Float16* propW2t= (_Float16*)alloc((size_t)NL * HD * HD * 2);
    _Float16* postW1t= (_Float16*)alloc((size_t)HD * HD * 2);
    _Float16* postW2t= (_Float16*)alloc((size_t)DOUT * HD * 2);
    int* gcount = (int*)alloc(NG * 4);
    int* goff   = (int*)alloc((NG + 1) * 4);
    int* deg    = (int*)alloc(NN * 4);
    int* eoff   = (int*)alloc((NN + 1) * 4);
    int* cursor = (int*)alloc(NN * 4);
    int* csr    = (int*)alloc((size_t)NE * 4);
    int* bsum   = (int*)alloc(1024 * 4);
    int* bexcl  = (int*)alloc(1024 * 4);
    _Float16* x16 = t16b;  // alias: only live before pre-GEMM1

    // ---------- graph meta ----------
    hipMemsetAsync(gcount, 0, NG * 4, stream);
    hipMemsetAsync(deg, 0, NN * 4, stream);
    hipMemsetAsync(cursor, 0, NN * 4, stream);
    hipLaunchKernelGGL(k_hist, dim3((NN + 255) / 256), dim3(256), 0, stream, batch, gcount, NN);
    hipLaunchKernelGGL(k_hist, dim3((NE + 255) / 256), dim3(256), 0, stream, e_dst, deg, NE);
    {
        int nbG = (NG + 255) / 256;
        hipLaunchKernelGGL(k_scan_part, dim3(nbG), dim3(256), 0, stream, gcount, bsum, NG);
        hipLaunchKernelGGL(k_scan_mid, dim3(1), dim3(1024), 0, stream, bsum, bexcl, nbG, goff, NG);
        hipLaunchKernelGGL(k_scan_out, dim3(nbG), dim3(256), 0, stream, gcount, bexcl, goff, NG);
        int nbN = (NN + 255) / 256;
        hipLaunchKernelGGL(k_scan_part, dim3(nbN), dim3(256), 0, stream, deg, bsum, NN);
        hipLaunchKernelGGL(k_scan_mid, dim3(1), dim3(1024), 0, stream, bsum, bexcl, nbN, eoff, NN);
        hipLaunchKernelGGL(k_scan_out, dim3(nbN), dim3(256), 0, stream, deg, bexcl, eoff, NN);
    }
    hipLaunchKernelGGL(k_fill_csr, dim3((NE + 255) / 256), dim3(256), 0, stream, e_src, e_dst, eoff, cursor, csr, NE);

    // ---------- weight convert + transpose ----------
    dim3 tb(32, 8);
    hipLaunchKernelGGL(k_wt, dim3(HD / 32, DIN / 32, 1), tb, 0, stream, pre_W1, preW1t, DIN, HD);
    hipLaunchKernelGGL(k_wt, dim3(HD / 32, HD / 32, 1), tb, 0, stream, pre_W2, preW2t, HD, HD);
    hipLaunchKernelGGL(k_wt, dim3(HD / 32, HD / 32, NL), tb, 0, stream, gin_W1, ginW1t, HD, HD);
    hipLaunchKernelGGL(k_wt, dim3(HD / 32, HD / 32, NL), tb, 0, stream, gin_W2, ginW2t, HD, HD);
    hipLaunchKernelGGL(k_wt, dim3(HD / 32, HD / 32, NL), tb, 0, stream, ffn_W1, ffnW1t, HD, HD);
    hipLaunchKernelGGL(k_wt, dim3(HD / 32, HD / 32, NL), tb, 0, stream, ffn_W2, ffnW2t, HD, HD);
    hipLaunchKernelGGL(k_wt, dim3(HD / 32, HD / 32, NL), tb, 0, stream, upd_W1, updW1t, HD, HD);
    hipLaunchKernelGGL(k_wt, dim3(H4 / 32, HD / 32, NL), tb, 0, stream, upd_W2, updW2t, HD, H4);
    hipLaunchKernelGGL(k_wt, dim3(HD / 32, H4 / 32, NL), tb, 0, stream, prop_W1, propW1t, H4, HD);
    hipLaunchKernelGGL(k_wt, dim3(HD / 32, HD / 32, NL), tb, 0, stream, prop_W2, propW2t, HD, HD);
    hipLaunchKernelGGL(k_wt, dim3(HD / 32, HD / 32, 1), tb, 0, stream, post_W1, postW1t, HD, HD);
    hipLaunchKernelGGL(k_wt, dim3(DOUT / 32, HD / 32, 1), tb, 0, stream, post_W2, postW2t, HD, DOUT);

    // x -> fp16
    int n4 = NN * DIN / 4;
    hipLaunchKernelGGL(k_cvt16, dim3((n4 + 255) / 256), dim3(256), 0, stream, x, x16, n4);

    // ---------- pre-FFNN ----------
    mg_gelu(stream, x16, preW1t, pre_b1, t16a, NN, HD, DIN);
    mg_both(stream, t16a, preW2t, pre_b2, h32, h16, NN, HD, HD);

    for (int i = 0; i < NL; ++i) {
        const _Float16* uW1 = updW1t + (size_t)i * HD * HD;
        const _Float16* uW2 = updW2t + (size_t)i * HD * H4;
        const _Float16* pW1 = propW1t + (size_t)i * H4 * HD;
        const _Float16* pW2 = propW2t + (size_t)i * HD * HD;
        const _Float16* gW1 = ginW1t + (size_t)i * HD * HD;
        const _Float16* gW2 = ginW2t + (size_t)i * HD * HD;
        const _Float16* fW1 = ffnW1t + (size_t)i * HD * HD;
        const _Float16* fW2 = ffnW2t + (size_t)i * HD * HD;

        // virtual-node path (M = NG = 512) via proven k_mgemm
        hipLaunchKernelGGL(k_pool16, dim3(NG), dim3(HD), 0, stream, h16, goff, pool16);
        mg_gelu(stream, pool16, uW1, upd_b1 + (size_t)i * HD, u16, NG, HD, HD);
        mg_bias2_16(stream, u16, uW2, upd_b2 + (size_t)i * H4, vn, vb16, NG, H4, HD);
        mg_gelu(stream, vb16, pW1, prop_b1 + (size_t)i * HD, p16, NG, HD, H4);
        mg_f32only(stream, p16, pW2, prop_b2 + (size_t)i * HD, outvn32, NG, HD, HD);

        // GIN: t16a = agg(h16); t16b = gelu(t16a@W1+b); g32 = t16b@W2+b + h32
        hipLaunchKernelGGL(k_agg16, dim3(NN / 4), dim3(256), 0, stream, h16, eoff, csr, t16a);
        mg_gelu(stream, t16a, gW1, gin_b1 + (size_t)i * HD, t16b, NN, HD, HD);
        mg_res32(stream, t16b, gW2, gin_b2 + (size_t)i * HD, h32, g32, NN, HD, HD);

        // BatchNorm (fp32 stats on g32; apply in-place; t16a = fp16 bn+outvn)
        hipMemsetAsync(bnstat, 0, 2 * HD * 4, stream);
        hipLaunchKernelGGL(k_bn_stats32, dim3((NN + 255) / 256), dim3(256), 0, stream, g32, bnstat);
        hipLaunchKernelGGL(k_bn_final, dim3(1), dim3(HD), 0, stream, bnstat,
                           bn_gamma + (size_t)i * HD, bn_beta + (size_t)i * HD, bnscale, bnshift);
        hipLaunchKernelGGL(k_bn_apply32, dim3((NN * 64 + 255) / 256), dim3(256), 0, stream,
                           g32, bnscale, bnshift, outvn32, batch, t16a);

        // FFN: t16b = gelu(t16a@W1+b); h32/h16 = t16b@W2+b + g32(bn'd)
        mg_gelu(stream, t16a, fW1, ffn_b1 + (size_t)i * HD, t16b, NN, HD, HD);
        mg_res_both(stream, t16b, fW2, ffn_b2 + (size_t)i * HD, g32, h32, h16, NN, HD, HD);
    }

    // ---------- post ----------
    hipLaunchKernelGGL(k_pool16, dim3(NG), dim3(HD), 0, stream, h16, goff, pool16);
    mg_gelu(stream, pool16, postW1t, post_b1, u16, NG, HD, HD);
    mg_f32only(stream, u16, postW2t, post_b2, out, NG, DOUT, HD);
}

// Round 6
// 2176.548 us; speedup vs baseline: 2.0402x; 1.0523x over previous
//
#include <hip/hip_runtime.h>
#include <hip/hip_bf16.h>
#include <math.h>

#define NN 50000
#define NNP 50048          // padded to multiple of 128
#define NE 800000
#define NG 512
#define DIN 128
#define HD 256
#define DOUT 128
#define NL 5
#define H4 1024

typedef _Float16 f16x8 __attribute__((ext_vector_type(8)));
typedef _Float16 f16x4 __attribute__((ext_vector_type(4)));
typedef float f32x4 __attribute__((ext_vector_type(4)));

__device__ __forceinline__ float gelu_exact(float x) {
    return 0.5f * x * (1.0f + erff(x * 0.70710678118654752f));
}

__device__ __forceinline__ void gl_lds16(const _Float16* g, _Float16* l) {
    __builtin_amdgcn_global_load_lds(
        (const __attribute__((address_space(1))) unsigned int*)g,
        (__attribute__((address_space(3))) unsigned int*)l, 16, 0, 0);
}

// ---------------- graph meta ----------------
__global__ void k_hist(const int* __restrict__ idx, int* __restrict__ cnt, int n) {
    int i = blockIdx.x * blockDim.x + threadIdx.x;
    if (i < n) atomicAdd(&cnt[idx[i]], 1);
}

__global__ void k_scan_part(const int* __restrict__ in, int* __restrict__ bsum, int n) {
    __shared__ int buf[256];
    int i = blockIdx.x * 256 + threadIdx.x;
    buf[threadIdx.x] = (i < n) ? in[i] : 0;
    __syncthreads();
    for (int off = 128; off > 0; off >>= 1) {
        if (threadIdx.x < off) buf[threadIdx.x] += buf[threadIdx.x + off];
        __syncthreads();
    }
    if (threadIdx.x == 0) bsum[blockIdx.x] = buf[0];
}

// single block: exclusive scan of nb block sums (nb<=1024); also writes out[n]=total
__global__ void k_scan_mid(const int* __restrict__ bsum, int* __restrict__ bexcl, int nb,
                           int* __restrict__ out, int n) {
    __shared__ int buf[1024];
    int t = threadIdx.x;
    int v = (t < nb) ? bsum[t] : 0;
    buf[t] = v;
    __syncthreads();
    for (int off = 1; off < 1024; off <<= 1) {
        int x = (t >= off) ? buf[t - off] : 0;
        __syncthreads();
        buf[t] += x;
        __syncthreads();
    }
    if (t < nb) bexcl[t] = buf[t] - v;
    if (t == 1023) out[n] = buf[1023];
}

__global__ void k_scan_out(const int* __restrict__ in, const int* __restrict__ bexcl,
                           int* __restrict__ out, int n) {
    __shared__ int buf[256];
    int i = blockIdx.x * 256 + threadIdx.x;
    int t = threadIdx.x;
    int v = (i < n) ? in[i] : 0;
    buf[t] = v;
    __syncthreads();
    for (int off = 1; off < 256; off <<= 1) {
        int x = (t >= off) ? buf[t - off] : 0;
        __syncthreads();
        buf[t] += x;
        __syncthreads();
    }
    if (i < n) out[i] = bexcl[blockIdx.x] + buf[t] - v;
}

__global__ void k_fill_csr(const int* __restrict__ src, const int* __restrict__ dst,
                           const int* __restrict__ eoff, int* __restrict__ cursor,
                           int* __restrict__ csr, int n) {
    int e = blockIdx.x * blockDim.x + threadIdx.x;
    if (e < n) {
        int d = dst[e];
        int p = atomicAdd(&cursor[d], 1);
        csr[eoff[d] + p] = src[e];
    }
}

// ---------------- converts ----------------
__global__ void k_cvt16(const float* __restrict__ in, _Float16* __restrict__ out, int n4) {
    int i = blockIdx.x * blockDim.x + threadIdx.x;
    if (i < n4) {
        float4 v = *(const float4*)&in[i * 4];
        f16x4 o = { (_Float16)v.x, (_Float16)v.y, (_Float16)v.z, (_Float16)v.w };
        *(f16x4*)&out[i * 4] = o;
    }
}

// transpose + convert: Wt[l][n][k] = (fp16) W[l][k][n]
__global__ void k_wt(const float* __restrict__ W, _Float16* __restrict__ Wt, int K, int N) {
    __shared__ float tile[32][33];
    size_t mat = (size_t)K * N;
    W += blockIdx.z * mat;
    Wt += blockIdx.z * mat;
    int n0 = blockIdx.x * 32, k0 = blockIdx.y * 32;
    for (int i = threadIdx.y; i < 32; i += 8)
        tile[i][threadIdx.x] = W[(size_t)(k0 + i) * N + n0 + threadIdx.x];
    __syncthreads();
    for (int i = threadIdx.y; i < 32; i += 8)
        Wt[(size_t)(n0 + i) * K + k0 + threadIdx.x] = (_Float16)tile[threadIdx.x][i];
}

// ---------------- pooling / aggregation ----------------
__global__ void k_pool16(const _Float16* __restrict__ h16, const int* __restrict__ goff,
                         _Float16* __restrict__ pool) {
    int g = blockIdx.x;
    int c = threadIdx.x;
    int s = goff[g], e = goff[g + 1];
    float acc = 0.f;
    for (int r = s; r < e; ++r) acc += (float)h16[(size_t)r * HD + c];
    int cnt = e - s;
    pool[g * HD + c] = (_Float16)(acc / (float)(cnt > 0 ? cnt : 1));
}

// one wave per node; 32 lanes x f16x8 cover the 256-col row. Half-waves take
// even/odd edges with WAVE-UNIFORM loop bounds; __shfl always fully active.
// 8 edges/iter => 4 gathers in flight per half-wave.
__global__ __launch_bounds__(256) void k_agg16(const _Float16* __restrict__ h16,
                                               const int* __restrict__ eoff,
                                               const int* __restrict__ csr,
                                               _Float16* __restrict__ out) {
    int node = blockIdx.x * 4 + (threadIdx.x >> 6);
    int lane = threadIdx.x & 63;
    int half = lane >> 5, l = lane & 31;
    f16x8 mine = *(const f16x8*)&h16[(size_t)node * HD + l * 8];
    float acc[8];
#pragma unroll
    for (int q = 0; q < 8; ++q) acc[q] = half ? 0.f : (float)mine[q];
    int s = eoff[node], e = eoff[node + 1];
    for (int base = s; base < e; base += 64) {
        int myi = base + lane;
        int vidx = (myi < e) ? csr[myi] : 0;
        int cnt = min(64, e - base);
        int jj = 0;
        for (; jj + 7 < cnt; jj += 8) {
            int s0 = __shfl(vidx, jj + half);
            int s1 = __shfl(vidx, jj + 2 + half);
            int s2 = __shfl(vidx, jj + 4 + half);
            int s3 = __shfl(vidx, jj + 6 + half);
            f16x8 v0 = *(const f16x8*)&h16[(size_t)s0 * HD + l * 8];
            f16x8 v1 = *(const f16x8*)&h16[(size_t)s1 * HD + l * 8];
            f16x8 v2 = *(const f16x8*)&h16[(size_t)s2 * HD + l * 8];
            f16x8 v3 = *(const f16x8*)&h16[(size_t)s3 * HD + l * 8];
#pragma unroll
            for (int q = 0; q < 8; ++q)
                acc[q] += ((float)v0[q] + (float)v1[q]) + ((float)v2[q] + (float)v3[q]);
        }
        for (; jj + 3 < cnt; jj += 4) {
            int s0 = __shfl(vidx, jj + half);
            int s1 = __shfl(vidx, jj + 2 + half);
            f16x8 v0 = *(const f16x8*)&h16[(size_t)s0 * HD + l * 8];
            f16x8 v1 = *(const f16x8*)&h16[(size_t)s1 * HD + l * 8];
#pragma unroll
            for (int q = 0; q < 8; ++q) acc[q] += (float)v0[q] + (float)v1[q];
        }
        for (; jj < cnt; jj += 2) {
            int i0 = jj + half;
            int s0 = __shfl(vidx, i0);
            if (i0 < cnt) {
                f16x8 v0 = *(const f16x8*)&h16[(size_t)s0 * HD + l * 8];
#pragma unroll
                for (int q = 0; q < 8; ++q) acc[q] += (float)v0[q];
            }
        }
    }
#pragma unroll
    for (int q = 0; q < 8; ++q) acc[q] += __shfl_xor(acc[q], 32);
    if (!half) {
        f16x8 o;
#pragma unroll
        for (int q = 0; q < 8; ++q) o[q] = (_Float16)acc[q];
        *(f16x8*)&out[(size_t)node * HD + l * 8] = o;
    }
}

// ---------------- batch norm finalize (also re-zeroes stat for next layer) ----
__global__ void k_bn_final(float* __restrict__ stat,
                           const float* __restrict__ gamma, const float* __restrict__ beta,
                           float* __restrict__ scale, float* __restrict__ shift) {
    int c = threadIdx.x;
    float mu = stat[c] * (1.0f / NN);
    float var = stat[HD + c] * (1.0f / NN) - mu * mu;
    float rs = rsqrtf(var + 1e-5f);
    float sc = rs * gamma[c];
    scale[c] = sc;
    shift[c] = beta[c] - mu * sc;
    stat[c] = 0.f;
    stat[HD + c] = 0.f;
}

// reads raw g32, writes fp16 (bn(g32) + outvn[batch]) FFN input (no g32 rewrite)
__global__ __launch_bounds__(256) void k_bn_apply32(const float* __restrict__ g2,
                                                    const float* __restrict__ scale,
                                                    const float* __restrict__ shift,
                                                    const float* __restrict__ outvn,
                                                    const int* __restrict__ batch,
                                                    _Float16* __restrict__ ffin) {
    int chunk = blockIdx.x * 256 + threadIdx.x;  // 4 floats each
    if (chunk >= NN * 64) return;
    int node = chunk >> 6, cg = chunk & 63;
    float4 v = *(const float4*)&g2[(size_t)chunk * 4];
    int b = batch[node];
    float4 sc = *(const float4*)&scale[cg * 4];
    float4 sh = *(const float4*)&shift[cg * 4];
    float4 ov = *(const float4*)&outvn[(size_t)b * HD + cg * 4];
    f16x4 f = { (_Float16)(v.x * sc.x + sh.x + ov.x),
                (_Float16)(v.y * sc.y + sh.y + ov.y),
                (_Float16)(v.z * sc.z + sh.z + ov.z),
                (_Float16)(v.w * sc.w + sh.w + ov.w) };
    *(f16x4*)&ffin[(size_t)chunk * 4] = f;
}

// ---------------- MFMA fp16 GEMM (128x128 tile, double-buffered) ----------------
// RES: +R[m][n] (fp32). RESBN: +R[m][n]*bnsc[n]+bnsh[n]. BIAS2: +bias2[n].
// STATS: atomically accumulate column sums of (v, v^2) into stat[0..HD-1], stat[HD..]
template <bool GELU, bool RES, bool RESBN, bool BIAS2, bool STATS, bool O32, bool O16>
__global__ __launch_bounds__(256) void k_mgemm(const _Float16* __restrict__ A,
                                               const _Float16* __restrict__ Wt,
                                               const float* __restrict__ bias,
                                               const float* __restrict__ bias2,
                                               const float* __restrict__ R,
                                               const float* __restrict__ bnsc,
                                               const float* __restrict__ bnsh,
                                               float* __restrict__ stat,
                                               float* __restrict__ C32,
                                               _Float16* __restrict__ C16,
                                               int M, int N, int K) {
    __shared__ _Float16 As[2][4][128][8];
    __shared__ _Float16 Bs[2][4][128][8];
    const int t = threadIdx.x;
    const int w = t >> 6, lane = t & 63;
    const int wr = w & 1, wc = w >> 1;
    const int m0 = blockIdx.y * 128, n0 = blockIdx.x * 128;
    const int kb = lane >> 4, fr = lane & 15;

    f32x4 acc[4][4];
#pragma unroll
    for (int mi = 0; mi < 4; ++mi)
#pragma unroll
        for (int ni = 0; ni < 4; ++ni) acc[mi][ni] = (f32x4){0.f, 0.f, 0.f, 0.f};

    const _Float16* gA0 = A + (size_t)(m0 + lane) * K + w * 8;
    const _Float16* gA1 = A + (size_t)(m0 + 64 + lane) * K + w * 8;
    const _Float16* gB0 = Wt + (size_t)(n0 + lane) * K + w * 8;
    const _Float16* gB1 = Wt + (size_t)(n0 + 64 + lane) * K + w * 8;

    const int nt = K >> 5;
    gl_lds16(gA0, &As[0][w][0][0]);
    gl_lds16(gA1, &As[0][w][64][0]);
    gl_lds16(gB0, &Bs[0][w][0][0]);
    gl_lds16(gB1, &Bs[0][w][64][0]);
    __syncthreads();
    for (int tt = 0; tt < nt; ++tt) {
        const int cur = tt & 1;
        if (tt + 1 < nt) {
            int k0 = (tt + 1) << 5;
            gl_lds16(gA0 + k0, &As[cur ^ 1][w][0][0]);
            gl_lds16(gA1 + k0, &As[cur ^ 1][w][64][0]);
            gl_lds16(gB0 + k0, &Bs[cur ^ 1][w][0][0]);
            gl_lds16(gB1 + k0, &Bs[cur ^ 1][w][64][0]);
        }
        f16x8 af[4], bf[4];
#pragma unroll
        for (int mi = 0; mi < 4; ++mi)
            af[mi] = *(const f16x8*)&As[cur][kb][wr * 64 + mi * 16 + fr][0];
#pragma unroll
        for (int ni = 0; ni < 4; ++ni)
            bf[ni] = *(const f16x8*)&Bs[cur][kb][wc * 64 + ni * 16 + fr][0];
#pragma unroll
        for (int mi = 0; mi < 4; ++mi)
#pragma unroll
            for (int ni = 0; ni < 4; ++ni)
                acc[mi][ni] = __builtin_amdgcn_mfma_f32_16x16x32_f16(af[mi], bf[ni], acc[mi][ni], 0, 0, 0);
        __syncthreads();
    }

    const int rr = lane >> 4;
    float cs[4] = {0.f, 0.f, 0.f, 0.f}, cq[4] = {0.f, 0.f, 0.f, 0.f};
#pragma unroll
    for (int mi = 0; mi < 4; ++mi) {
#pragma unroll
        for (int reg = 0; reg < 4; ++reg) {
            int m = m0 + wr * 64 + mi * 16 + rr * 4 + reg;
            if (m < M) {
#pragma unroll
                for (int ni = 0; ni < 4; ++ni) {
                    int n = n0 + wc * 64 + ni * 16 + fr;
                    float v = acc[mi][ni][reg] + bias[n];
                    if (BIAS2) v += bias2[n];
                    if (GELU) v = gelu_exact(v);
                    if (RES) v += R[(size_t)m * N + n];
                    if (RESBN) v += R[(size_t)m * N + n] * bnsc[n] + bnsh[n];
                    if (O32) C32[(size_t)m * N + n] = v;
                    if (O16) C16[(size_t)m * N + n] = (_Float16)v;
                    if (STATS) { cs[ni] += v; cq[ni] += v * v; }
                }
            }
        }
    }
    if constexpr (STATS) {
        __shared__ float sred[2][128], qred[2][128];
#pragma unroll
        for (int ni = 0; ni < 4; ++ni) {
            cs[ni] += __shfl_xor(cs[ni], 16); cs[ni] += __shfl_xor(cs[ni], 32);
            cq[ni] += __shfl_xor(cq[ni], 16); cq[ni] += __shfl_xor(cq[ni], 32);
        }
        if (rr == 0) {
#pragma unroll
            for (int ni = 0; ni < 4; ++ni) {
                sred[wr][wc * 64 + ni * 16 + fr] = cs[ni];
                qred[wr][wc * 64 + ni * 16 + fr] = cq[ni];
            }
        }
        __syncthreads();
        if (t < 128) {
            atomicAdd(&stat[n0 + t], sred[0][t] + sred[1][t]);
            atomicAdd(&stat[HD + n0 + t], qred[0][t] + qred[1][t]);
        }
    }
}

// helpers
static inline void mg_gelu(hipStream_t st, const _Float16* A, const _Float16* Wt,
                           const float* bias, _Float16* C16, int M, int N, int K) {
    dim3 g(N / 128, (M + 127) / 128), b(256);
    k_mgemm<true, false, false, false, false, false, true><<<g, b, 0, st>>>(
        A, Wt, bias, nullptr, nullptr, nullptr, nullptr, nullptr, nullptr, C16, M, N, K);
}
static inline void mg_both(hipStream_t st, const _Float16* A, const _Float16* Wt,
                           const float* bias, float* C32, _Float16* C16, int M, int N, int K) {
    dim3 g(N / 128, (M + 127) / 128), b(256);
    k_mgemm<false, false, false, false, false, true, true><<<g, b, 0, st>>>(
        A, Wt, bias, nullptr, nullptr, nullptr, nullptr, nullptr, C32, C16, M, N, K);
}
static inline void mg_res32_stats(hipStream_t st, const _Float16* A, const _Float16* Wt,
                                  const float* bias, const float* R, float* stat,
                                  float* C32, int M, int N, int K) {
    dim3 g(N / 128, (M + 127) / 128), b(256);
    k_mgemm<false, true, false, false, true, true, false><<<g, b, 0, st>>>(
        A, Wt, bias, nullptr, R, nullptr, nullptr, stat, C32, nullptr, M, N, K);
}
static inline void mg_resbn_both(hipStream_t st, const _Float16* A, const _Float16* Wt,
                                 const float* bias, const float* R, const float* bnsc,
                                 const float* bnsh, float* C32, _Float16* C16,
                                 int M, int N, int K) {
    dim3 g(N / 128, (M + 127) / 128), b(256);
    k_mgemm<false, false, true, false, false, true, true><<<g, b, 0, st>>>(
        A, Wt, bias, nullptr, R, bnsc, bnsh, nullptr, C32, C16, M, N, K);
}
static inline void mg_bias2_16(hipStream_t st, const _Float16* A, const _Float16* Wt,
                               const float* bias, const float* bias2, _Float16* C16,
                               int M, int N, int K) {
    dim3 g(N / 128, (M + 127) / 128), b(256);
    k_mgemm<false, false, false, true, false, false, true><<<g, b, 0, st>>>(
        A, Wt, bias, bias2, nullptr, nullptr, nullptr, nullptr, nullptr, C16, M, N, K);
}
static inline void mg_f32only(hipStream_t st, const _Float16* A, const _Float16* Wt,
                              const float* bias, float* C32, int M, int N, int K) {
    dim3 g(N / 128, (M + 127) / 128), b(256);
    k_mgemm<false, false, false, false, false, true, false><<<g, b, 0, st>>>(
        A, Wt, bias, nullptr, nullptr, nullptr, nullptr, nullptr, C32, nullptr, M, N, K);
}

extern "C" void kernel_launch(void* const* d_in, const int* in_sizes, int n_in,
                              void* d_out, int out_size, void* d_ws, size_t ws_size,
                              hipStream_t stream) {
    const float* x       = (const float*)d_in[0];
    const int*   ei      = (const int*)d_in[1];
    const int*   batch   = (const int*)d_in[2];
    const float* pre_W1  = (const float*)d_in[3];
    const float* pre_b1  = (const float*)d_in[4];
    const float* pre_W2  = (const float*)d_in[5];
    const float* pre_b2  = (const float*)d_in[6];
    const float* gin_W1  = (const float*)d_in[7];
    const float* gin_b1  = (const float*)d_in[8];
    const float* gin_W2  = (const float*)d_in[9];
    const float* gin_b2  = (const float*)d_in[10];
    const float* ffn_W1  = (const float*)d_in[11];
    const float* ffn_b1  = (const float*)d_in[12];
    const float* ffn_W2  = (const float*)d_in[13];
    const float* ffn_b2  = (const float*)d_in[14];
    const float* upd_W1  = (const float*)d_in[15];
    const float* upd_b1  = (const float*)d_in[16];
    const float* upd_W2  = (const float*)d_in[17];
    const float* upd_b2  = (const float*)d_in[18];
    const float* prop_W1 = (const float*)d_in[19];
    const float* prop_b1 = (const float*)d_in[20];
    const float* prop_W2 = (const float*)d_in[21];
    const float* prop_b2 = (const float*)d_in[22];
    const float* bn_gamma= (const float*)d_in[23];
    const float* bn_beta = (const float*)d_in[24];
    const float* vn      = (const float*)d_in[25];
    const float* post_W1 = (const float*)d_in[26];
    const float* post_b1 = (const float*)d_in[27];
    const float* post_W2 = (const float*)d_in[28];
    const float* post_b2 = (const float*)d_in[29];
    float* out = (float*)d_out;

    const int* e_src = ei;
    const int* e_dst = ei + NE;

    // ---------- workspace layout ----------
    char* p = (char*)d_ws;
    auto alloc = [&](size_t bytes) -> char* {
        char* r = p;
        p += (bytes + 255) & ~(size_t)255;
        return r;
    };
    float*    h32    = (float*)alloc((size_t)NNP * HD * 4);   // fp32 backbone
    float*    g32    = (float*)alloc((size_t)NNP * HD * 4);   // gin2 out (raw, never bn'd in place)
    _Float16* h16    = (_Float16*)alloc((size_t)NNP * HD * 2);
    _Float16* t16a   = (_Float16*)alloc((size_t)NNP * HD * 2);
    _Float16* t16b   = (_Float16*)alloc((size_t)NNP * HD * 2);  // aliases x16 pre-launch
    _Float16* pool16 = (_Float16*)alloc((size_t)NG * HD * 2);
    _Float16* u16    = (_Float16*)alloc((size_t)NG * HD * 2);
    _Float16* vb16   = (_Float16*)alloc((size_t)NG * H4 * 2);
    _Float16* p16    = (_Float16*)alloc((size_t)NG * HD * 2);
    float*    outvn32= (float*)alloc((size_t)NG * HD * 4);
    float*    bnstat = (float*)alloc(2 * HD * 4);
    float*    bnscale= (float*)alloc(HD * 4);
    float*    bnshift= (float*)alloc(HD * 4);
    _Float16* preW1t = (_Float16*)alloc((size_t)HD * DIN * 2);
    _Float16* preW2t = (_Float16*)alloc((size_t)HD * HD * 2);
    _Float16* ginW1t = (_Float16*)alloc((size_t)NL * HD * HD * 2);
    _Float16* ginW2t = (_Float16*)alloc((size_t)NL * HD * HD * 2);
    _Float16* ffnW1t = (_Float16*)alloc((size_t)NL * HD * HD * 2);
    _Float16* ffnW2t = (_Float16*)alloc((size_t)NL * HD * HD * 2);
    _Float16* updW1t = (_Float16*)alloc((size_t)NL * HD * HD * 2);
    _Float16* updW2t = (_Float16*)alloc((size_t)NL * HD * H4 * 2);
    _Float16* propW1t= (_Float16*)alloc((size_t)NL * H4 * HD * 2);
    _Float16* propW2t= (_Float16*)alloc((size_t)NL * HD * HD * 2);
    _Float16* postW1t= (_Float16*)alloc((size_t)HD * HD * 2);
    _Float16* postW2t= (_Float16*)alloc((size_t)DOUT * HD * 2);
    int* gcount = (int*)alloc(NG * 4);
    int* goff   = (int*)alloc((NG + 1) * 4);
    int* deg    = (int*)alloc(NN * 4);
    int* eoff   = (int*)alloc((NN + 1) * 4);
    int* cursor = (int*)alloc(NN * 4);
    int* csr    = (int*)alloc((size_t)NE * 4);
    int* bsum   = (int*)alloc(1024 * 4);
    int* bexcl  = (int*)alloc(1024 * 4);
    _Float16* x16 = t16b;  // alias: only live before pre-GEMM1

    // ---------- zero counters (gcount..cursor contiguous span) + bnstat ----------
    {
        size_t span = (size_t)((char*)(cursor + NN) - (char*)gcount);
        hipMemsetAsync(gcount, 0, span, stream);
        hipMemsetAsync(bnstat, 0, 2 * HD * 4, stream);
    }
    hipLaunchKernelGGL(k_hist, dim3((NN + 255) / 256), dim3(256), 0, stream, batch, gcount, NN);
    hipLaunchKernelGGL(k_hist, dim3((NE + 255) / 256), dim3(256), 0, stream, e_dst, deg, NE);
    {
        int nbG = (NG + 255) / 256;
        hipLaunchKernelGGL(k_scan_part, dim3(nbG), dim3(256), 0, stream, gcount, bsum, NG);
        hipLaunchKernelGGL(k_scan_mid, dim3(1), dim3(1024), 0, stream, bsum, bexcl, nbG, goff, NG);
        hipLaunchKernelGGL(k_scan_out, dim3(nbG), dim3(256), 0, stream, gcount, bexcl, goff, NG);
        int nbN = (NN + 255) / 256;
        hipLaunchKernelGGL(k_scan_part, dim3(nbN), dim3(256), 0, stream, deg, bsum, NN);
        hipLaunchKernelGGL(k_scan_mid, dim3(1), dim3(1024), 0, stream, bsum, bexcl, nbN, eoff, NN);
        hipLaunchKernelGGL(k_scan_out, dim3(nbN), dim3(256), 0, stream, deg, bexcl, eoff, NN);
    }
    hipLaunchKernelGGL(k_fill_csr, dim3((NE + 255) / 256), dim3(256), 0, stream, e_src, e_dst, eoff, cursor, csr, NE);

    // ---------- weight convert + transpose ----------
    dim3 tb(32, 8);
    hipLaunchKernelGGL(k_wt, dim3(HD / 32, DIN / 32, 1), tb, 0, stream, pre_W1, preW1t, DIN, HD);
    hipLaunchKernelGGL(k_wt, dim3(HD / 32, HD / 32, 1), tb, 0, stream, pre_W2, preW2t, HD, HD);
    hipLaunchKernelGGL(k_wt, dim3(HD / 32, HD / 32, NL), tb, 0, stream, gin_W1, ginW1t, HD, HD);
    hipLaunchKernelGGL(k_wt, dim3(HD / 32, HD / 32, NL), tb, 0, stream, gin_W2, ginW2t, HD, HD);
    hipLaunchKernelGGL(k_wt, dim3(HD / 32, HD / 32, NL), tb, 0, stream, ffn_W1, ffnW1t, HD, HD);
    hipLaunchKernelGGL(k_wt, dim3(HD / 32, HD / 32, NL), tb, 0, stream, ffn_W2, ffnW2t, HD, HD);
    hipLaunchKernelGGL(k_wt, dim3(HD / 32, HD / 32, NL), tb, 0, stream, upd_W1, updW1t, HD, HD);
    hipLaunchKernelGGL(k_wt, dim3(H4 / 32, HD / 32, NL), tb, 0, stream, upd_W2, updW2t, HD, H4);
    hipLaunchKernelGGL(k_wt, dim3(HD / 32, H4 / 32, NL), tb, 0, stream, prop_W1, propW1t, H4, HD);
    hipLaunchKernelGGL(k_wt, dim3(HD / 32, HD / 32, NL), tb, 0, stream, prop_W2, propW2t, HD, HD);
    hipLaunchKernelGGL(k_wt, dim3(HD / 32, HD / 32, 1), tb, 0, stream, post_W1, postW1t, HD, HD);
    hipLaunchKernelGGL(k_wt, dim3(DOUT / 32, HD / 32, 1), tb, 0, stream, post_W2, postW2t, HD, DOUT);

    // x -> fp16
    int n4 = NN * DIN / 4;
    hipLaunchKernelGGL(k_cvt16, dim3((n4 + 255) / 256), dim3(256), 0, stream, x, x16, n4);

    // ---------- pre-FFNN ----------
    mg_gelu(stream, x16, preW1t, pre_b1, t16a, NN, HD, DIN);
    mg_both(stream, t16a, preW2t, pre_b2, h32, h16, NN, HD, HD);

    for (int i = 0; i < NL; ++i) {
        const _Float16* uW1 = updW1t + (size_t)i * HD * HD;
        const _Float16* uW2 = updW2t + (size_t)i * HD * H4;
        const _Float16* pW1 = propW1t + (size_t)i * H4 * HD;
        const _Float16* pW2 = propW2t + (size_t)i * HD * HD;
        const _Float16* gW1 = ginW1t + (size_t)i * HD * HD;
        const _Float16* gW2 = ginW2t + (size_t)i * HD * HD;
        const _Float16* fW1 = ffnW1t + (size_t)i * HD * HD;
        const _Float16* fW2 = ffnW2t + (size_t)i * HD * HD;

        // virtual-node path (M = NG = 512)
        hipLaunchKernelGGL(k_pool16, dim3(NG), dim3(HD), 0, stream, h16, goff, pool16);
        mg_gelu(stream, pool16, uW1, upd_b1 + (size_t)i * HD, u16, NG, HD, HD);
        mg_bias2_16(stream, u16, uW2, upd_b2 + (size_t)i * H4, vn, vb16, NG, H4, HD);
        mg_gelu(stream, vb16, pW1, prop_b1 + (size_t)i * HD, p16, NG, HD, H4);
        mg_f32only(stream, p16, pW2, prop_b2 + (size_t)i * HD, outvn32, NG, HD, HD);

        // GIN: t16a = agg(h16); t16b = gelu(t16a@W1+b); g32 = t16b@W2+b + h32 (+fused BN stats)
        hipLaunchKernelGGL(k_agg16, dim3(NN / 4), dim3(256), 0, stream, h16, eoff, csr, t16a);
        mg_gelu(stream, t16a, gW1, gin_b1 + (size_t)i * HD, t16b, NN, HD, HD);
        mg_res32_stats(stream, t16b, gW2, gin_b2 + (size_t)i * HD, h32, bnstat, g32, NN, HD, HD);

        // BN finalize (re-zeroes stat) + fp16 FFN input (raw g32 stays)
        hipLaunchKernelGGL(k_bn_final, dim3(1), dim3(HD), 0, stream, bnstat,
                           bn_gamma + (size_t)i * HD, bn_beta + (size_t)i * HD, bnscale, bnshift);
        hipLaunchKernelGGL(k_bn_apply32, dim3((NN * 64 + 255) / 256), dim3(256), 0, stream,
                           g32, bnscale, bnshift, outvn32, batch, t16a);

        // FFN: t16b = gelu(t16a@W1+b); h32/h16 = t16b@W2+b + (g32*scale+shift)
        mg_gelu(stream, t16a, fW1, ffn_b1 + (size_t)i * HD, t16b, NN, HD, HD);
        mg_resbn_both(stream, t16b, fW2, ffn_b2 + (size_t)i * HD, g32, bnscale, bnshift,
                      h32, h16, NN, HD, HD);
    }

    // ---------- post ----------
    hipLaunchKernelGGL(k_pool16, dim3(NG), dim3(HD), 0, stream, h16, goff, pool16);
    mg_gelu(stream, pool16, postW1t, post_b1, u16, NG, HD, HD);
    mg_f32only(stream, u16, postW2t, post_b2, out, NG, DOUT, HD);
}